// Round 2
// baseline (556.444 us; speedup 1.0000x reference)
//
#include <hip/hip_runtime.h>
#include <stdint.h>

typedef _Float16 half8 __attribute__((ext_vector_type(8)));
typedef float floatx4 __attribute__((ext_vector_type(4)));

__device__ __forceinline__ uint16_t f16bits(_Float16 h) {
  union { _Float16 f; uint16_t u; } x; x.f = h; return x.u;
}

// async global->LDS, 16B per lane; lds dst is wave-uniform base + lane*16
__device__ __forceinline__ void g2l16(const void* g, void* l) {
  __builtin_amdgcn_global_load_lds((const __attribute__((address_space(1))) void*)g,
                                   (__attribute__((address_space(3))) void*)l,
                                   16, 0, 0);
}

// ---------------- split fp32 -> f16 hi + f16 lo ----------------
__global__ __launch_bounds__(256) void split_f16_kernel(
    const float* __restrict__ x, uint16_t* __restrict__ hi,
    uint16_t* __restrict__ lo, int n4) {
  int i = blockIdx.x * 256 + threadIdx.x;
  if (i >= n4) return;
  float4 v = ((const float4*)x)[i];
  ushort4 h, l;
  _Float16 a;
  a = (_Float16)v.x; h.x = f16bits(a); l.x = f16bits((_Float16)(v.x - (float)a));
  a = (_Float16)v.y; h.y = f16bits(a); l.y = f16bits((_Float16)(v.y - (float)a));
  a = (_Float16)v.z; h.z = f16bits(a); l.z = f16bits((_Float16)(v.z - (float)a));
  a = (_Float16)v.w; h.w = f16bits(a); l.w = f16bits((_Float16)(v.w - (float)a));
  ((ushort4*)hi)[i] = h;
  ((ushort4*)lo)[i] = l;
}

// ---------------- fused H split + transpose ----------------
__global__ __launch_bounds__(256) void split_h_kernel(
    const float* __restrict__ src, uint16_t* __restrict__ hi,
    uint16_t* __restrict__ lo, uint16_t* __restrict__ ht) {
  __shared__ uint16_t tile[64][65];
  const int e0 = blockIdx.x * 64;
  const int t0 = blockIdx.y * 64;
  const size_t bb = (size_t)blockIdx.z << 20;  // 1024*1024 per batch
  const int r = threadIdx.x >> 4;        // 0..15
  const int c = (threadIdx.x & 15) * 4;  // 0..60
#pragma unroll
  for (int it = 0; it < 4; ++it) {
    const int tr = r + it * 16;
    const size_t idx = bb + (size_t)(t0 + tr) * 1024 + e0 + c;
    float4 v = *(const float4*)(src + idx);
    ushort4 h, l;
    _Float16 a;
    a = (_Float16)v.x; h.x = f16bits(a); l.x = f16bits((_Float16)(v.x - (float)a));
    a = (_Float16)v.y; h.y = f16bits(a); l.y = f16bits((_Float16)(v.y - (float)a));
    a = (_Float16)v.z; h.z = f16bits(a); l.z = f16bits((_Float16)(v.z - (float)a));
    a = (_Float16)v.w; h.w = f16bits(a); l.w = f16bits((_Float16)(v.w - (float)a));
    *(ushort4*)(hi + idx) = h;
    *(ushort4*)(lo + idx) = l;
    tile[c + 0][tr] = h.x;
    tile[c + 1][tr] = h.y;
    tile[c + 2][tr] = h.z;
    tile[c + 3][tr] = h.w;
  }
  __syncthreads();
#pragma unroll
  for (int it = 0; it < 4; ++it) {
    const int er = r + it * 16;
    ushort4 o;
    o.x = tile[er][c + 0];
    o.y = tile[er][c + 1];
    o.z = tile[er][c + 2];
    o.w = tile[er][c + 3];
    *(ushort4*)(ht + bb + (size_t)(e0 + er) * 1024 + t0 + c) = o;
  }
}

// ---------------- C = A * B^T  (256x256 tile, BK=32, 8 waves) ----------------
// A:(M,K) row-major f16 (hi[,lo]), B:(N,K) row-major f16 (hi[,lo]).
// SPLIT: acc += Ahi*Blo + Ahi*Bhi + Alo*Bhi  (double-f16 ~ fp32 accuracy;
//        per-element add order identical to the verified 128-tile version)
// K-loop = catalog "minimum 2-phase" dbuf recipe (T3): issue STAGE(next)
// at loop top, compute buf[cur], then ONE __syncthreads() per tile (emits
// vmcnt(0) lgkmcnt(0) + s_barrier = recipe's drain; stage latency is hidden
// under the ~96-MFMA compute phase).  setprio(1) around MFMA cluster (T5).
// GMAP 0: x = M-tile (lin%8 = m_t%8 partitions M across XCDs; W L2-resident)
// GMAP 1: x = batch (lin%8 = batch%8 -> 2 batches/XCD; a batch's A/B panels
//         stay on one XCD's L2), y = (m<<2)|n.
// MODE 0: write split f16 (Chi,Clo), add bias[col]
// MODE 1: write f32 Cf, add mask
// MODE 2: write f32 Cf
template <bool SPLIT, int MODE, int GMAP>
__global__ __launch_bounds__(512, 2) void gemm_bt(
    const uint16_t* __restrict__ Ahi, const uint16_t* __restrict__ Alo,
    const uint16_t* __restrict__ Bhi, const uint16_t* __restrict__ Blo,
    uint16_t* __restrict__ Chi, uint16_t* __restrict__ Clo,
    float* __restrict__ Cf, const float* __restrict__ mask,
    const float* __restrict__ bias, int N, int K,
    long batchA, long batchB, long batchC) {
  constexpr int NBUF = SPLIT ? 2 : 1;   // hi[,lo]
  // [dbuf][hi/lo][256 rows x 32 k]  (SPLIT: 128 KB total; else 64 KB)
  __shared__ __align__(16) uint16_t sA[2][NBUF][256 * 32];
  __shared__ __align__(16) uint16_t sB[2][NBUF][256 * 32];

  const int tid = threadIdx.x;
  const int lane = tid & 63;
  const int w = tid >> 6;             // wave 0..7
  const int wr = w >> 2, wc = w & 3;  // 2x4 wave grid; per-wave out 128x64
  const int quad = lane >> 4, l16 = lane & 15;

  int m_t, n_t, z;
  if constexpr (GMAP == 0) {
    m_t = blockIdx.x; n_t = blockIdx.y; z = 0;
  } else {
    z = blockIdx.x; m_t = blockIdx.y >> 2; n_t = blockIdx.y & 3;
  }
  const int m0 = m_t * 256;
  const int n0 = n_t * 256;
  const size_t zA = (size_t)z * batchA;
  const size_t zB = (size_t)z * batchB;
  const size_t zC = (size_t)z * batchC;

  // staging: wave w loads rows [w*32, w*32+32) of each 256x32 tile.
  // one g2l16 = 64 lanes * 16B = 16 rows of 64B; chunk is XOR-swizzled so the
  // compute-side ds_read_b128 is bank-spread (same scheme as the verified
  // 128-tile version).
  const int r0 = w * 32 + (lane >> 2);
  const int ldc = (((lane & 3) ^ ((lane >> 2) & 3)) * 16);  // byte chunk
  const size_t rowskip = (size_t)16 * K * 2;                // +16 rows, bytes

  const char* gAh = (const char*)(Ahi + zA + (size_t)(m0 + r0) * K) + ldc;
  const char* gBh = (const char*)(Bhi + zB + (size_t)(n0 + r0) * K) + ldc;
  const char* gAl = gAh;
  const char* gBl = gBh;
  if constexpr (SPLIT) {
    gAl = (const char*)(Alo + zA + (size_t)(m0 + r0) * K) + ldc;
    gBl = (const char*)(Blo + zB + (size_t)(n0 + r0) * K) + ldc;
  }

  auto stage = [&](int buf, int kb) {
    g2l16(gAh + kb, &sA[buf][0][(w * 32) * 32]);
    g2l16(gAh + rowskip + kb, &sA[buf][0][(w * 32 + 16) * 32]);
    g2l16(gBh + kb, &sB[buf][0][(w * 32) * 32]);
    g2l16(gBh + rowskip + kb, &sB[buf][0][(w * 32 + 16) * 32]);
    if constexpr (SPLIT) {
      g2l16(gAl + kb, &sA[buf][NBUF - 1][(w * 32) * 32]);
      g2l16(gAl + rowskip + kb, &sA[buf][NBUF - 1][(w * 32 + 16) * 32]);
      g2l16(gBl + kb, &sB[buf][NBUF - 1][(w * 32) * 32]);
      g2l16(gBl + rowskip + kb, &sB[buf][NBUF - 1][(w * 32 + 16) * 32]);
    }
  };

  // compute-phase LDS offsets (elements); chunk swizzled by row&3 == l16&3
  const int aoff = (wr * 128 + l16) * 32 + ((quad ^ (l16 & 3)) * 8);
  const int boff = (wc * 64 + l16) * 32 + ((quad ^ (l16 & 3)) * 8);

  floatx4 acc[8][4];
  floatx4 zero = {0.f, 0.f, 0.f, 0.f};
#pragma unroll
  for (int i = 0; i < 8; ++i)
#pragma unroll
    for (int j = 0; j < 4; ++j) acc[i][j] = zero;

  const int nkt = K >> 5;
  stage(0, 0);
  __syncthreads();  // prologue drain: buf0 ready
  int cur = 0;
  for (int kt = 0; kt < nkt; ++kt) {
    if (kt + 1 < nkt) stage(cur ^ 1, (kt + 1) * 64);  // issue-early (overlap)

    const uint16_t* pAh = &sA[cur][0][0];
    const uint16_t* pBh = &sB[cur][0][0];
    const uint16_t* pAl = &sA[cur][NBUF - 1][0];
    const uint16_t* pBl = &sB[cur][NBUF - 1][0];
    half8 fbh[4], fbl[4];
    if constexpr (SPLIT) {
#pragma unroll
      for (int j = 0; j < 4; ++j) fbl[j] = *(const half8*)&pBl[boff + j * 512];
    }
#pragma unroll
    for (int j = 0; j < 4; ++j) fbh[j] = *(const half8*)&pBh[boff + j * 512];
    __builtin_amdgcn_s_setprio(1);
#pragma unroll
    for (int i = 0; i < 8; ++i) {
      half8 fah = *(const half8*)&pAh[aoff + i * 512];
      if constexpr (SPLIT) {
        half8 fal = *(const half8*)&pAl[aoff + i * 512];
#pragma unroll
        for (int j = 0; j < 4; ++j)
          acc[i][j] = __builtin_amdgcn_mfma_f32_16x16x32_f16(fah, fbl[j], acc[i][j], 0, 0, 0);
#pragma unroll
        for (int j = 0; j < 4; ++j)
          acc[i][j] = __builtin_amdgcn_mfma_f32_16x16x32_f16(fah, fbh[j], acc[i][j], 0, 0, 0);
#pragma unroll
        for (int j = 0; j < 4; ++j)
          acc[i][j] = __builtin_amdgcn_mfma_f32_16x16x32_f16(fal, fbh[j], acc[i][j], 0, 0, 0);
      } else {
#pragma unroll
        for (int j = 0; j < 4; ++j)
          acc[i][j] = __builtin_amdgcn_mfma_f32_16x16x32_f16(fah, fbh[j], acc[i][j], 0, 0, 0);
      }
    }
    __builtin_amdgcn_s_setprio(0);
    // ONE barrier per K-tile: emits s_waitcnt vmcnt(0) lgkmcnt(0) + s_barrier
    // => this wave's ds_reads of buf[cur] done AND next tile's stage landed.
    __syncthreads();
    cur ^= 1;
  }

  // epilogue: C/D layout col=lane&15, row=quad*4+r (m89/m91 verified)
  const int crow0 = m0 + wr * 128 + quad * 4;
  const int ccol0 = n0 + wc * 64 + l16;
#pragma unroll
  for (int j = 0; j < 4; ++j) {
    const int col = ccol0 + j * 16;
    float bj = 0.f;
    if constexpr (MODE == 0) bj = bias[col];
#pragma unroll
    for (int i = 0; i < 8; ++i) {
#pragma unroll
      for (int r = 0; r < 4; ++r) {
        const int row = crow0 + i * 16 + r;
        const size_t idx = zC + (size_t)row * N + col;
        float v = acc[i][j][r];
        if constexpr (MODE == 0) {
          v += bj;
          _Float16 h = (_Float16)v;
          Chi[idx] = f16bits(h);
          Clo[idx] = f16bits((_Float16)(v - (float)h));
        } else if constexpr (MODE == 1) {
          Cf[idx] = v + mask[idx];
        } else {
          Cf[idx] = v;
        }
      }
    }
  }
}

// ---------------- row softmax: fp32 scores -> f16 probs ----------------
__global__ __launch_bounds__(256) void softmax_kernel(
    const float* __restrict__ sc, uint16_t* __restrict__ p) {
  const int row = blockIdx.x;
  const float* x = sc + (size_t)row * 1024;
  const int t = threadIdx.x;
  float4 v = ((const float4*)x)[t];
  float m = fmaxf(fmaxf(v.x, v.y), fmaxf(v.z, v.w));
#pragma unroll
  for (int off = 32; off; off >>= 1) m = fmaxf(m, __shfl_xor(m, off));
  __shared__ float redm[4];
  __shared__ float reds[4];
  const int wv = t >> 6, ln = t & 63;
  if (ln == 0) redm[wv] = m;
  __syncthreads();
  m = fmaxf(fmaxf(redm[0], redm[1]), fmaxf(redm[2], redm[3]));
  float e0 = __expf(v.x - m), e1 = __expf(v.y - m);
  float e2 = __expf(v.z - m), e3 = __expf(v.w - m);
  float s = e0 + e1 + e2 + e3;
#pragma unroll
  for (int off = 32; off; off >>= 1) s += __shfl_xor(s, off);
  if (ln == 0) reds[wv] = s;
  __syncthreads();
  s = reds[0] + reds[1] + reds[2] + reds[3];
  float inv = 1.f / s;
  ushort4 o;
  o.x = f16bits((_Float16)(e0 * inv));
  o.y = f16bits((_Float16)(e1 * inv));
  o.z = f16bits((_Float16)(e2 * inv));
  o.w = f16bits((_Float16)(e3 * inv));
  ((ushort4*)(p + (size_t)row * 1024))[t] = o;
}

// ---------------- H (b,t,e) f32 -> H_T (b,e,t) f16 (fallback path) --------
__global__ __launch_bounds__(256) void transpose_f16_kernel(
    const float* __restrict__ src, uint16_t* __restrict__ dst) {
  __shared__ uint16_t tile[64][65];
  const int e0 = blockIdx.x * 64;
  const int t0 = blockIdx.y * 64;
  const size_t bb = (size_t)blockIdx.z << 20;
  const int r = threadIdx.x >> 4;
  const int c = (threadIdx.x & 15) * 4;
#pragma unroll
  for (int it = 0; it < 4; ++it) {
    const int tr = r + it * 16;
    float4 v = *(const float4*)(src + bb + (size_t)(t0 + tr) * 1024 + e0 + c);
    tile[c + 0][tr] = f16bits((_Float16)v.x);
    tile[c + 1][tr] = f16bits((_Float16)v.y);
    tile[c + 2][tr] = f16bits((_Float16)v.z);
    tile[c + 3][tr] = f16bits((_Float16)v.w);
  }
  __syncthreads();
#pragma unroll
  for (int it = 0; it < 4; ++it) {
    const int er = r + it * 16;
    ushort4 o;
    o.x = tile[er][c + 0];
    o.y = tile[er][c + 1];
    o.z = tile[er][c + 2];
    o.w = tile[er][c + 3];
    *(ushort4*)(dst + bb + (size_t)(e0 + er) * 1024 + t0 + c) = o;
  }
}

extern "C" void kernel_launch(void* const* d_in, const int* in_sizes, int n_in,
                              void* d_out, int out_size, void* d_ws, size_t ws_size,
                              hipStream_t stream) {
  (void)in_sizes; (void)n_in; (void)out_size;
  const float* S    = (const float*)d_in[0];  // (16,1024,1024)
  const float* H    = (const float*)d_in[1];  // (16,1024,1024)
  const float* mask = (const float*)d_in[2];  // (16,1024,1024)
  const float* Ww   = (const float*)d_in[3];  // (1024,1024)
  const float* Wb   = (const float*)d_in[4];  // (1024,)
  float* out = (float*)d_out;
  char* ws = (char*)d_ws;
  const size_t MB = 1024ull * 1024ull;

  // workspace layout:
  uint16_t* Whi  = (uint16_t*)(ws + 0 * MB);    // 2MB
  uint16_t* Wlo  = (uint16_t*)(ws + 2 * MB);    // 2MB
  uint16_t* Pjhi = (uint16_t*)(ws + 4 * MB);    // 32MB  projection hi
  uint16_t* Pjlo = (uint16_t*)(ws + 36 * MB);   // 32MB  projection lo
  uint16_t* Hhi  = (uint16_t*)(ws + 68 * MB);   // 32MB
  uint16_t* Hlo  = (uint16_t*)(ws + 100 * MB);  // 32MB
  uint16_t* Shi  = (uint16_t*)(ws + 132 * MB);  // 32MB (dead after gemm1)
  uint16_t* Slo  = (uint16_t*)(ws + 164 * MB);  // 32MB (dead after gemm1)
  float*    SC   = (float*)(ws + 132 * MB);     // 64MB scores, aliases Shi/Slo
  uint16_t* PR   = (uint16_t*)(ws + 68 * MB);   // 32MB probs, aliases Hhi

  const bool roomy = ws_size >= 229ull * MB;
  uint16_t* HT = roomy ? (uint16_t*)(ws + 196 * MB)   // 32MB dedicated
                       : (uint16_t*)(ws + 100 * MB);  // aliases Hlo (late write)

  // split inputs into f16 hi/lo
  split_f16_kernel<<<16384, 256, 0, stream>>>(S, Shi, Slo, 4 * 1024 * 1024);
  split_f16_kernel<<<1024, 256, 0, stream>>>(Ww, Whi, Wlo, 256 * 1024);
  if (roomy) {
    split_h_kernel<<<dim3(16, 16, 16), 256, 0, stream>>>(H, Hhi, Hlo, HT);
  } else {
    split_f16_kernel<<<16384, 256, 0, stream>>>(H, Hhi, Hlo, 4 * 1024 * 1024);
  }

  // S_ = S @ W^T + b   (GMAP 0; 64x4 = 256 wgs = 1/CU)
  gemm_bt<true, 0, 0><<<dim3(64, 4, 1), 512, 0, stream>>>(
      Shi, Slo, Whi, Wlo, Pjhi, Pjlo, nullptr, nullptr, Wb,
      1024, 1024, 0, 0, 0);
  // scores = S_ @ H^T + mask  (GMAP 1; 16 batches x 16 tiles = 256 wgs)
  gemm_bt<true, 1, 1><<<dim3(16, 16, 1), 512, 0, stream>>>(
      Pjhi, Pjlo, Hhi, Hlo, nullptr, nullptr, SC, mask, nullptr,
      1024, 1024, 1048576, 1048576, 1048576);
  // P = softmax(scores) rowwise -> f16
  softmax_kernel<<<16384, 256, 0, stream>>>(SC, PR);
  if (!roomy) {
    transpose_f16_kernel<<<dim3(16, 16, 16), 256, 0, stream>>>(H, HT);
  }
  // out = P @ H  ==  P @ (H_T)^T
  gemm_bt<false, 2, 1><<<dim3(16, 16, 1), 512, 0, stream>>>(
      PR, nullptr, HT, nullptr, nullptr, nullptr, out, nullptr, nullptr,
      1024, 1024, 1048576, 1048576, 1048576);
}

// Round 3
// 538.805 us; speedup vs baseline: 1.0327x; 1.0327x over previous
//
#include <hip/hip_runtime.h>
#include <stdint.h>

typedef _Float16 half8 __attribute__((ext_vector_type(8)));
typedef float floatx4 __attribute__((ext_vector_type(4)));

__device__ __forceinline__ uint16_t f16bits(_Float16 h) {
  union { _Float16 f; uint16_t u; } x; x.f = h; return x.u;
}

// async global->LDS, 16B per lane; lds dst is wave-uniform base + lane*16
__device__ __forceinline__ void g2l16(const void* g, void* l) {
  __builtin_amdgcn_global_load_lds((const __attribute__((address_space(1))) void*)g,
                                   (__attribute__((address_space(3))) void*)l,
                                   16, 0, 0);
}

// ---------------- split fp32 -> f16 hi + f16 lo ----------------
__global__ __launch_bounds__(256) void split_f16_kernel(
    const float* __restrict__ x, uint16_t* __restrict__ hi,
    uint16_t* __restrict__ lo, int n4) {
  int i = blockIdx.x * 256 + threadIdx.x;
  if (i >= n4) return;
  float4 v = ((const float4*)x)[i];
  ushort4 h, l;
  _Float16 a;
  a = (_Float16)v.x; h.x = f16bits(a); l.x = f16bits((_Float16)(v.x - (float)a));
  a = (_Float16)v.y; h.y = f16bits(a); l.y = f16bits((_Float16)(v.y - (float)a));
  a = (_Float16)v.z; h.z = f16bits(a); l.z = f16bits((_Float16)(v.z - (float)a));
  a = (_Float16)v.w; h.w = f16bits(a); l.w = f16bits((_Float16)(v.w - (float)a));
  ((ushort4*)hi)[i] = h;
  ((ushort4*)lo)[i] = l;
}

// ---------------- fused H split + transpose ----------------
__global__ __launch_bounds__(256) void split_h_kernel(
    const float* __restrict__ src, uint16_t* __restrict__ hi,
    uint16_t* __restrict__ lo, uint16_t* __restrict__ ht) {
  __shared__ uint16_t tile[64][65];
  const int e0 = blockIdx.x * 64;
  const int t0 = blockIdx.y * 64;
  const size_t bb = (size_t)blockIdx.z << 20;  // 1024*1024 per batch
  const int r = threadIdx.x >> 4;        // 0..15
  const int c = (threadIdx.x & 15) * 4;  // 0..60
#pragma unroll
  for (int it = 0; it < 4; ++it) {
    const int tr = r + it * 16;
    const size_t idx = bb + (size_t)(t0 + tr) * 1024 + e0 + c;
    float4 v = *(const float4*)(src + idx);
    ushort4 h, l;
    _Float16 a;
    a = (_Float16)v.x; h.x = f16bits(a); l.x = f16bits((_Float16)(v.x - (float)a));
    a = (_Float16)v.y; h.y = f16bits(a); l.y = f16bits((_Float16)(v.y - (float)a));
    a = (_Float16)v.z; h.z = f16bits(a); l.z = f16bits((_Float16)(v.z - (float)a));
    a = (_Float16)v.w; h.w = f16bits(a); l.w = f16bits((_Float16)(v.w - (float)a));
    *(ushort4*)(hi + idx) = h;
    *(ushort4*)(lo + idx) = l;
    tile[c + 0][tr] = h.x;
    tile[c + 1][tr] = h.y;
    tile[c + 2][tr] = h.z;
    tile[c + 3][tr] = h.w;
  }
  __syncthreads();
#pragma unroll
  for (int it = 0; it < 4; ++it) {
    const int er = r + it * 16;
    ushort4 o;
    o.x = tile[er][c + 0];
    o.y = tile[er][c + 1];
    o.z = tile[er][c + 2];
    o.w = tile[er][c + 3];
    *(ushort4*)(ht + bb + (size_t)(e0 + er) * 1024 + t0 + c) = o;
  }
}

// ---- C = A * B^T  (256x256 tile, BK=32, 8 waves, 5-slot ring pipeline) ----
// A:(M,K) row-major f16 (hi[,lo]), B:(N,K) row-major f16 (hi[,lo]).
// SPLIT: acc += Ahi*Blo + Ahi*Bhi + Alo*Bhi (per-element order identical to
//        the verified baseline -> bit-identical output).
// Pipeline (T3+T4 from the verified m201 template, adapted to SPLIT):
//   ring of 5 LDS "units" (unit = {A-half,B-half}x{hi,lo} for one K-step
//   half: 128 rows x 32 k).  K-step t reads units 2t,2t+1 (slots sl0,sl0+1),
//   issues units 2t+3 (phase 0) and 2t+4 (phase 2) into slots sl0+3,sl0+4
//   (mod 5; never the read slots).  Boundary drain waits vmcnt(4) -- the
//   newest unit stays IN FLIGHT across the barrier (never drain to 0 in the
//   steady state).  4 phases per K-step, each: {ds_read subtile || issue} ->
//   s_barrier -> lgkmcnt(0) -> setprio(1) -> 24 MFMA -> setprio(0) -> s_barrier.
// GMAP 0: x = M-tile (lin%8 = m_t%8; W stays L2-resident per XCD)
// GMAP 1: x = batch (lin%8 = batch%8; batch panels stay on one XCD's L2)
// MODE 0: write split f16 (Chi,Clo), add bias[col]
// MODE 1: write f32 Cf, add mask
// MODE 2: write f32 Cf
template <bool SPLIT, int MODE, int GMAP>
__global__ __launch_bounds__(512, 2) void gemm_bt(
    const uint16_t* __restrict__ Ahi, const uint16_t* __restrict__ Alo,
    const uint16_t* __restrict__ Bhi, const uint16_t* __restrict__ Blo,
    uint16_t* __restrict__ Chi, uint16_t* __restrict__ Clo,
    float* __restrict__ Cf, const float* __restrict__ mask,
    const float* __restrict__ bias, int N, int K,
    long batchA, long batchB, long batchC) {
  constexpr int UNIT = SPLIT ? 16384 : 8192;  // elems per ring unit
  constexpr int OAL = 4096;                   // A-lo offset (SPLIT only)
  constexpr int OBH = SPLIT ? 8192 : 4096;    // B-hi offset
  constexpr int OBL = 12288;                  // B-lo offset (SPLIT only)
  // 5 units: SPLIT 160KB (full CU LDS), non-split 80KB
  __shared__ __align__(16) uint16_t lds[5 * UNIT];

  const int tid = threadIdx.x;
  const int lane = tid & 63;
  const int w = tid >> 6;             // wave 0..7
  const int wr = w >> 2, wc = w & 3;  // 2x4 wave grid; per-wave out 128x64
  const int quad = lane >> 4, l16 = lane & 15;

  int m_t, n_t, z;
  if constexpr (GMAP == 0) {
    m_t = blockIdx.x; n_t = blockIdx.y; z = 0;
  } else {
    z = blockIdx.x; m_t = blockIdx.y >> 2; n_t = blockIdx.y & 3;
  }
  const int m0 = m_t * 256;
  const int n0 = n_t * 256;
  const size_t zA = (size_t)z * batchA;
  const size_t zB = (size_t)z * batchB;
  const size_t zC = (size_t)z * batchC;

  // staging: per unit, wave w loads rows [w*16, w*16+16) of the 128-row half
  // of each sub-matrix; one g2l16 per sub-matrix (64 lanes*16B = 16 rows of
  // 64B).  Chunk is XOR-swizzled on the GLOBAL side (linear LDS dst).
  const int r4 = w * 16 + (lane >> 2);                      // row in half
  const int ldc = (((lane & 3) ^ ((lane >> 2) & 3)) * 16);  // byte chunk
  const size_t halfskip = (size_t)128 * K * 2;              // +128 rows, bytes

  const char* gAh = (const char*)(Ahi + zA + (size_t)(m0 + r4) * K) + ldc;
  const char* gBh = (const char*)(Bhi + zB + (size_t)(n0 + r4) * K) + ldc;
  const char* gAl = gAh;
  const char* gBl = gBh;
  if constexpr (SPLIT) {
    gAl = (const char*)(Alo + zA + (size_t)(m0 + r4) * K) + ldc;
    gBl = (const char*)(Blo + zB + (size_t)(n0 + r4) * K) + ldc;
  }

  auto issue_unit = [&](int u, int sl) {
    const int tt = u >> 1;
    const size_t go = (size_t)(u & 1) * halfskip + (size_t)tt * 64;
    uint16_t* ub = &lds[sl * UNIT] + w * 512;
    g2l16(gAh + go, ub);
    if constexpr (SPLIT) g2l16(gAl + go, ub + OAL);
    g2l16(gBh + go, ub + OBH);
    if constexpr (SPLIT) g2l16(gBl + go, ub + OBL);
  };

  // compute-phase LDS offsets (elems, relative to the unit's sub-matrix)
  const int aoff = l16 * 32 + ((quad ^ (l16 & 3)) * 8);
  const int boff = ((wc & 1) * 64 + l16) * 32 + ((quad ^ (l16 & 3)) * 8);

  floatx4 acc[8][4];
  floatx4 zero = {0.f, 0.f, 0.f, 0.f};
#pragma unroll
  for (int i = 0; i < 8; ++i)
#pragma unroll
    for (int j = 0; j < 4; ++j) acc[i][j] = zero;

  const int nkt = K >> 5;
  const int NU = nkt * 2;

  // prologue: units 0,1,2 -> slots 0,1,2; need 0,1 done, unit 2 may fly
  issue_unit(0, 0);
  issue_unit(1, 1);
  issue_unit(2, 2);
  if constexpr (SPLIT)
    asm volatile("s_waitcnt vmcnt(4)" ::: "memory");
  else
    asm volatile("s_waitcnt vmcnt(2)" ::: "memory");
  __builtin_amdgcn_s_barrier();
  asm volatile("" ::: "memory");

  int sl0 = 0;  // slot of unit 2t
  for (int t = 0; t < nkt; ++t) {
    const int sl1 = (sl0 + 1 == 5) ? 0 : sl0 + 1;
    const int si0 = (sl0 + 3 >= 5) ? sl0 - 2 : sl0 + 3;  // unit 2t+3
    const int si1 = (sl0 + 4 >= 5) ? sl0 - 1 : sl0 + 4;  // unit 2t+4
    const uint16_t* uA = &lds[(wr ? sl1 : sl0) * UNIT];
    const uint16_t* uB = &lds[((wc >> 1) ? sl1 : sl0) * UNIT];
    half8 fbh[4], fbl[4];
#pragma unroll
    for (int p = 0; p < 4; ++p) {
      half8 fah[2], fal[2];
      if (p == 0) {
        if constexpr (SPLIT) {
#pragma unroll
          for (int j = 0; j < 4; ++j)
            fbl[j] = *(const half8*)&uB[OBL + boff + j * 512];
        }
#pragma unroll
        for (int j = 0; j < 4; ++j)
          fbh[j] = *(const half8*)&uB[OBH + boff + j * 512];
      }
      fah[0] = *(const half8*)&uA[aoff + (2 * p) * 512];
      fah[1] = *(const half8*)&uA[aoff + (2 * p + 1) * 512];
      if constexpr (SPLIT) {
        fal[0] = *(const half8*)&uA[OAL + aoff + (2 * p) * 512];
        fal[1] = *(const half8*)&uA[OAL + aoff + (2 * p + 1) * 512];
      }
      if (p == 0 && 2 * t + 3 < NU) issue_unit(2 * t + 3, si0);
      if (p == 2 && 2 * t + 4 < NU) issue_unit(2 * t + 4, si1);
      asm volatile("" ::: "memory");
      __builtin_amdgcn_s_barrier();
      asm volatile("s_waitcnt lgkmcnt(0)" ::: "memory");
      __builtin_amdgcn_sched_barrier(0);
      __builtin_amdgcn_s_setprio(1);
#pragma unroll
      for (int ii = 0; ii < 2; ++ii) {
        const int i = 2 * p + ii;
        if constexpr (SPLIT) {
#pragma unroll
          for (int j = 0; j < 4; ++j)
            acc[i][j] = __builtin_amdgcn_mfma_f32_16x16x32_f16(fah[ii], fbl[j], acc[i][j], 0, 0, 0);
#pragma unroll
          for (int j = 0; j < 4; ++j)
            acc[i][j] = __builtin_amdgcn_mfma_f32_16x16x32_f16(fah[ii], fbh[j], acc[i][j], 0, 0, 0);
#pragma unroll
          for (int j = 0; j < 4; ++j)
            acc[i][j] = __builtin_amdgcn_mfma_f32_16x16x32_f16(fal[ii], fbh[j], acc[i][j], 0, 0, 0);
        } else {
#pragma unroll
          for (int j = 0; j < 4; ++j)
            acc[i][j] = __builtin_amdgcn_mfma_f32_16x16x32_f16(fah[ii], fbh[j], acc[i][j], 0, 0, 0);
        }
      }
      __builtin_amdgcn_s_setprio(0);
      if (p < 3) {
        asm volatile("" ::: "memory");
        __builtin_amdgcn_s_barrier();
      }
    }
    // K-step boundary: counted drain (newest unit stays in flight), barrier
    if (t + 2 < nkt) {
      if constexpr (SPLIT)
        asm volatile("s_waitcnt vmcnt(4)" ::: "memory");
      else
        asm volatile("s_waitcnt vmcnt(2)" ::: "memory");
    } else if (t + 1 < nkt) {
      asm volatile("s_waitcnt vmcnt(0)" ::: "memory");
    }
    asm volatile("" ::: "memory");
    __builtin_amdgcn_s_barrier();
    asm volatile("" ::: "memory");
    sl0 = (sl0 + 2 >= 5) ? sl0 - 3 : sl0 + 2;
  }

  // epilogue: C/D layout col=lane&15, row=quad*4+r (m89/m91 verified)
  const int crow0 = m0 + wr * 128 + quad * 4;
  const int ccol0 = n0 + wc * 64 + l16;
#pragma unroll
  for (int j = 0; j < 4; ++j) {
    const int col = ccol0 + j * 16;
    float bj = 0.f;
    if constexpr (MODE == 0) bj = bias[col];
#pragma unroll
    for (int i = 0; i < 8; ++i) {
#pragma unroll
      for (int r = 0; r < 4; ++r) {
        const int row = crow0 + i * 16 + r;
        const size_t idx = zC + (size_t)row * N + col;
        float v = acc[i][j][r];
        if constexpr (MODE == 0) {
          v += bj;
          _Float16 h = (_Float16)v;
          Chi[idx] = f16bits(h);
          Clo[idx] = f16bits((_Float16)(v - (float)h));
        } else if constexpr (MODE == 1) {
          Cf[idx] = v + mask[idx];
        } else {
          Cf[idx] = v;
        }
      }
    }
  }
}

// ---------------- row softmax: fp32 scores -> f16 probs ----------------
__global__ __launch_bounds__(256) void softmax_kernel(
    const float* __restrict__ sc, uint16_t* __restrict__ p) {
  const int row = blockIdx.x;
  const float* x = sc + (size_t)row * 1024;
  const int t = threadIdx.x;
  float4 v = ((const float4*)x)[t];
  float m = fmaxf(fmaxf(v.x, v.y), fmaxf(v.z, v.w));
#pragma unroll
  for (int off = 32; off; off >>= 1) m = fmaxf(m, __shfl_xor(m, off));
  __shared__ float redm[4];
  __shared__ float reds[4];
  const int wv = t >> 6, ln = t & 63;
  if (ln == 0) redm[wv] = m;
  __syncthreads();
  m = fmaxf(fmaxf(redm[0], redm[1]), fmaxf(redm[2], redm[3]));
  float e0 = __expf(v.x - m), e1 = __expf(v.y - m);
  float e2 = __expf(v.z - m), e3 = __expf(v.w - m);
  float s = e0 + e1 + e2 + e3;
#pragma unroll
  for (int off = 32; off; off >>= 1) s += __shfl_xor(s, off);
  if (ln == 0) reds[wv] = s;
  __syncthreads();
  s = reds[0] + reds[1] + reds[2] + reds[3];
  float inv = 1.f / s;
  ushort4 o;
  o.x = f16bits((_Float16)(e0 * inv));
  o.y = f16bits((_Float16)(e1 * inv));
  o.z = f16bits((_Float16)(e2 * inv));
  o.w = f16bits((_Float16)(e3 * inv));
  ((ushort4*)(p + (size_t)row * 1024))[t] = o;
}

// ---------------- H (b,t,e) f32 -> H_T (b,e,t) f16 (fallback path) --------
__global__ __launch_bounds__(256) void transpose_f16_kernel(
    const float* __restrict__ src, uint16_t* __restrict__ dst) {
  __shared__ uint16_t tile[64][65];
  const int e0 = blockIdx.x * 64;
  const int t0 = blockIdx.y * 64;
  const size_t bb = (size_t)blockIdx.z << 20;
  const int r = threadIdx.x >> 4;
  const int c = (threadIdx.x & 15) * 4;
#pragma unroll
  for (int it = 0; it < 4; ++it) {
    const int tr = r + it * 16;
    float4 v = *(const float4*)(src + bb + (size_t)(t0 + tr) * 1024 + e0 + c);
    tile[c + 0][tr] = f16bits((_Float16)v.x);
    tile[c + 1][tr] = f16bits((_Float16)v.y);
    tile[c + 2][tr] = f16bits((_Float16)v.z);
    tile[c + 3][tr] = f16bits((_Float16)v.w);
  }
  __syncthreads();
#pragma unroll
  for (int it = 0; it < 4; ++it) {
    const int er = r + it * 16;
    ushort4 o;
    o.x = tile[er][c + 0];
    o.y = tile[er][c + 1];
    o.z = tile[er][c + 2];
    o.w = tile[er][c + 3];
    *(ushort4*)(dst + bb + (size_t)(e0 + er) * 1024 + t0 + c) = o;
  }
}

extern "C" void kernel_launch(void* const* d_in, const int* in_sizes, int n_in,
                              void* d_out, int out_size, void* d_ws, size_t ws_size,
                              hipStream_t stream) {
  (void)in_sizes; (void)n_in; (void)out_size;
  const float* S    = (const float*)d_in[0];  // (16,1024,1024)
  const float* H    = (const float*)d_in[1];  // (16,1024,1024)
  const float* mask = (const float*)d_in[2];  // (16,1024,1024)
  const float* Ww   = (const float*)d_in[3];  // (1024,1024)
  const float* Wb   = (const float*)d_in[4];  // (1024,)
  float* out = (float*)d_out;
  char* ws = (char*)d_ws;
  const size_t MB = 1024ull * 1024ull;

  // workspace layout:
  uint16_t* Whi  = (uint16_t*)(ws + 0 * MB);    // 2MB
  uint16_t* Wlo  = (uint16_t*)(ws + 2 * MB);    // 2MB
  uint16_t* Pjhi = (uint16_t*)(ws + 4 * MB);    // 32MB  projection hi
  uint16_t* Pjlo = (uint16_t*)(ws + 36 * MB);   // 32MB  projection lo
  uint16_t* Hhi  = (uint16_t*)(ws + 68 * MB);   // 32MB
  uint16_t* Hlo  = (uint16_t*)(ws + 100 * MB);  // 32MB
  uint16_t* Shi  = (uint16_t*)(ws + 132 * MB);  // 32MB (dead after gemm1)
  uint16_t* Slo  = (uint16_t*)(ws + 164 * MB);  // 32MB (dead after gemm1)
  float*    SC   = (float*)(ws + 132 * MB);     // 64MB scores, aliases Shi/Slo
  uint16_t* PR   = (uint16_t*)(ws + 68 * MB);   // 32MB probs, aliases Hhi

  const bool roomy = ws_size >= 229ull * MB;
  uint16_t* HT = roomy ? (uint16_t*)(ws + 196 * MB)   // 32MB dedicated
                       : (uint16_t*)(ws + 100 * MB);  // aliases Hlo (late write)

  // split inputs into f16 hi/lo
  split_f16_kernel<<<16384, 256, 0, stream>>>(S, Shi, Slo, 4 * 1024 * 1024);
  split_f16_kernel<<<1024, 256, 0, stream>>>(Ww, Whi, Wlo, 256 * 1024);
  if (roomy) {
    split_h_kernel<<<dim3(16, 16, 16), 256, 0, stream>>>(H, Hhi, Hlo, HT);
  } else {
    split_f16_kernel<<<16384, 256, 0, stream>>>(H, Hhi, Hlo, 4 * 1024 * 1024);
  }

  // S_ = S @ W^T + b   (GMAP 0; 64x4 = 256 wgs = 1/CU)
  gemm_bt<true, 0, 0><<<dim3(64, 4, 1), 512, 0, stream>>>(
      Shi, Slo, Whi, Wlo, Pjhi, Pjlo, nullptr, nullptr, Wb,
      1024, 1024, 0, 0, 0);
  // scores = S_ @ H^T + mask  (GMAP 1; 16 batches x 16 tiles = 256 wgs)
  gemm_bt<true, 1, 1><<<dim3(16, 16, 1), 512, 0, stream>>>(
      Pjhi, Pjlo, Hhi, Hlo, nullptr, nullptr, SC, mask, nullptr,
      1024, 1024, 1048576, 1048576, 1048576);
  // P = softmax(scores) rowwise -> f16
  softmax_kernel<<<16384, 256, 0, stream>>>(SC, PR);
  if (!roomy) {
    transpose_f16_kernel<<<dim3(16, 16, 16), 256, 0, stream>>>(H, HT);
  }
  // out = P @ H  ==  P @ (H_T)^T
  gemm_bt<false, 2, 1><<<dim3(16, 16, 1), 512, 0, stream>>>(
      PR, nullptr, HT, nullptr, nullptr, nullptr, out, nullptr, nullptr,
      1024, 1024, 1048576, 1048576, 1048576);
}

// Round 4
// 506.295 us; speedup vs baseline: 1.0991x; 1.0642x over previous
//
#include <hip/hip_runtime.h>
#include <stdint.h>

typedef _Float16 half8 __attribute__((ext_vector_type(8)));
typedef float floatx4 __attribute__((ext_vector_type(4)));

__device__ __forceinline__ uint16_t f16bits(_Float16 h) {
  union { _Float16 f; uint16_t u; } x; x.f = h; return x.u;
}

// async global->LDS, 16B per lane; lds dst is wave-uniform base + lane*16
__device__ __forceinline__ void g2l16(const void* g, void* l) {
  __builtin_amdgcn_global_load_lds((const __attribute__((address_space(1))) void*)g,
                                   (__attribute__((address_space(3))) void*)l,
                                   16, 0, 0);
}

// ---------------- split fp32 -> f16 hi + f16 lo ----------------
__global__ __launch_bounds__(256) void split_f16_kernel(
    const float* __restrict__ x, uint16_t* __restrict__ hi,
    uint16_t* __restrict__ lo, int n4) {
  int i = blockIdx.x * 256 + threadIdx.x;
  if (i >= n4) return;
  float4 v = ((const float4*)x)[i];
  ushort4 h, l;
  _Float16 a;
  a = (_Float16)v.x; h.x = f16bits(a); l.x = f16bits((_Float16)(v.x - (float)a));
  a = (_Float16)v.y; h.y = f16bits(a); l.y = f16bits((_Float16)(v.y - (float)a));
  a = (_Float16)v.z; h.z = f16bits(a); l.z = f16bits((_Float16)(v.z - (float)a));
  a = (_Float16)v.w; h.w = f16bits(a); l.w = f16bits((_Float16)(v.w - (float)a));
  ((ushort4*)hi)[i] = h;
  ((ushort4*)lo)[i] = l;
}

// ---------------- fused H split + transpose ----------------
// H (b,t,e) f32 -> Hhi,Hlo (b,t,e) f16  AND  HT (b,e,t) f16(=hi)
__global__ __launch_bounds__(256) void split_h_kernel(
    const float* __restrict__ src, uint16_t* __restrict__ hi,
    uint16_t* __restrict__ lo, uint16_t* __restrict__ ht) {
  __shared__ uint16_t tile[64][65];
  const int e0 = blockIdx.x * 64;
  const int t0 = blockIdx.y * 64;
  const size_t bb = (size_t)blockIdx.z << 20;  // 1024*1024 per batch
  const int r = threadIdx.x >> 4;        // 0..15
  const int c = (threadIdx.x & 15) * 4;  // 0..60
#pragma unroll
  for (int it = 0; it < 4; ++it) {
    const int tr = r + it * 16;
    const size_t idx = bb + (size_t)(t0 + tr) * 1024 + e0 + c;
    float4 v = *(const float4*)(src + idx);
    ushort4 h, l;
    _Float16 a;
    a = (_Float16)v.x; h.x = f16bits(a); l.x = f16bits((_Float16)(v.x - (float)a));
    a = (_Float16)v.y; h.y = f16bits(a); l.y = f16bits((_Float16)(v.y - (float)a));
    a = (_Float16)v.z; h.z = f16bits(a); l.z = f16bits((_Float16)(v.z - (float)a));
    a = (_Float16)v.w; h.w = f16bits(a); l.w = f16bits((_Float16)(v.w - (float)a));
    *(ushort4*)(hi + idx) = h;
    *(ushort4*)(lo + idx) = l;
    tile[c + 0][tr] = h.x;
    tile[c + 1][tr] = h.y;
    tile[c + 2][tr] = h.z;
    tile[c + 3][tr] = h.w;
  }
  __syncthreads();
#pragma unroll
  for (int it = 0; it < 4; ++it) {
    const int er = r + it * 16;
    ushort4 o;
    o.x = tile[er][c + 0];
    o.y = tile[er][c + 1];
    o.z = tile[er][c + 2];
    o.w = tile[er][c + 3];
    *(ushort4*)(ht + bb + (size_t)(e0 + er) * 1024 + t0 + c) = o;
  }
}

// ---------------- C = A * B^T  (128x128 tile, BK=32, dbuf) ----------------
// A:(M,K) row-major f16 (hi[,lo]), B:(N,K) row-major f16 (hi[,lo]).
// SPLIT: acc += Ahi*Blo + Ahi*Bhi + Alo*Bhi  (double-f16 ~ fp32 accuracy)
// K-loop = T3 minimal dbuf recipe: STAGE(next buf) at loop top, compute
// current buf, ONE __syncthreads per step (drains vmcnt+lgkmcnt then
// barrier).  Stage latency hides under ~compute phase; 2 blocks/CU (SPLIT)
// add inter-block overlap on top (m114).
// GMAP 0: x = M-tile (lin%8 partitions M across XCDs; W L2-resident)
// GMAP 1: x = batch (lin%8 partitions batches across XCDs), y = (m<<3)|n.
// MODE 0: write split f16 (Chi,Clo), add bias[col]
// MODE 1: write f32 Cf, add mask
// MODE 2: write f32 Cf
template <bool SPLIT, int MODE, int GMAP>
__global__ __launch_bounds__(256, 4) void gemm_bt(
    const uint16_t* __restrict__ Ahi, const uint16_t* __restrict__ Alo,
    const uint16_t* __restrict__ Bhi, const uint16_t* __restrict__ Blo,
    uint16_t* __restrict__ Chi, uint16_t* __restrict__ Clo,
    float* __restrict__ Cf, const float* __restrict__ mask,
    const float* __restrict__ bias, int N, int K,
    long batchA, long batchB, long batchC) {
  constexpr int NBUF = SPLIT ? 2 : 1;
  constexpr int LOI = SPLIT ? 1 : 0;
  // [dbuf][hi/lo][128 rows x 32 k]: SPLIT 64KB total, non-split 32KB
  __shared__ __align__(16) uint16_t sA[2][NBUF][128 * 32];
  __shared__ __align__(16) uint16_t sB[2][NBUF][128 * 32];

  const int tid = threadIdx.x;
  const int lane = tid & 63;
  const int w = tid >> 6;            // wave 0..3
  const int wr = w >> 1, wc = w & 1; // 2x2 wave grid, 64x64 per wave
  const int quad = lane >> 4, l16 = lane & 15;

  int m_t, n_t, z;
  if constexpr (GMAP == 0) {
    m_t = blockIdx.x; n_t = blockIdx.y; z = 0;
  } else {
    z = blockIdx.x; m_t = blockIdx.y >> 3; n_t = blockIdx.y & 7;
  }
  const int m0 = m_t * 128;
  const int n0 = n_t * 128;
  const size_t zA = (size_t)z * batchA;
  const size_t zB = (size_t)z * batchB;
  const size_t zC = (size_t)z * batchC;

  // staging: wave w loads rows [w*32, w*32+32) of each 128x32 tile, 2x 1KB
  const int r0 = w * 32 + (lane >> 2);                       // row for q=0 chunk
  const int ldc = (((lane & 3) ^ ((lane >> 2) & 3)) * 16);   // XOR-swizzled chunk

  const char* gAh0 = (const char*)(Ahi + zA + (size_t)(m0 + r0) * K) + ldc;
  const char* gAh1 = gAh0 + (size_t)16 * K * 2;
  const char* gBh0 = (const char*)(Bhi + zB + (size_t)(n0 + r0) * K) + ldc;
  const char* gBh1 = gBh0 + (size_t)16 * K * 2;
  const char* gAl0 = gAh0; const char* gAl1 = gAh1;
  const char* gBl0 = gBh0; const char* gBl1 = gBh1;
  if constexpr (SPLIT) {
    gAl0 = (const char*)(Alo + zA + (size_t)(m0 + r0) * K) + ldc;
    gAl1 = gAl0 + (size_t)16 * K * 2;
    gBl0 = (const char*)(Blo + zB + (size_t)(n0 + r0) * K) + ldc;
    gBl1 = gBl0 + (size_t)16 * K * 2;
  }

  auto stage = [&](int buf, int kt) {
    const int kb = kt * 64;  // 32 f16 = 64B per row per K-tile
    g2l16(gAh0 + kb, &sA[buf][0][(w * 32) * 32]);
    g2l16(gAh1 + kb, &sA[buf][0][(w * 32 + 16) * 32]);
    g2l16(gBh0 + kb, &sB[buf][0][(w * 32) * 32]);
    g2l16(gBh1 + kb, &sB[buf][0][(w * 32 + 16) * 32]);
    if constexpr (SPLIT) {
      g2l16(gAl0 + kb, &sA[buf][LOI][(w * 32) * 32]);
      g2l16(gAl1 + kb, &sA[buf][LOI][(w * 32 + 16) * 32]);
      g2l16(gBl0 + kb, &sB[buf][LOI][(w * 32) * 32]);
      g2l16(gBl1 + kb, &sB[buf][LOI][(w * 32 + 16) * 32]);
    }
  };

  // compute-phase LDS offsets (elements); chunk swizzled by row&3 == l16&3
  const int aoff = (wr * 64 + l16) * 32 + ((quad ^ (l16 & 3)) * 8);
  const int boff = (wc * 64 + l16) * 32 + ((quad ^ (l16 & 3)) * 8);

  floatx4 acc[4][4];
  floatx4 zero = {0.f, 0.f, 0.f, 0.f};
#pragma unroll
  for (int i = 0; i < 4; ++i)
#pragma unroll
    for (int j = 0; j < 4; ++j) acc[i][j] = zero;

  const int nkt = K >> 5;
  stage(0, 0);
  __syncthreads();  // prologue: buf0 ready
  int cur = 0;
  for (int kt = 0; kt < nkt; ++kt) {
    if (kt + 1 < nkt) stage(cur ^ 1, kt + 1);  // issue-early into other buf

    // 3 sequential product passes -> max ~3x4 half8 frags live
    half8 fa[4];
#pragma unroll
    for (int i = 0; i < 4; ++i) fa[i] = *(const half8*)&sA[cur][0][aoff + i * 512];
    if constexpr (SPLIT) {
      half8 fbl[4];
#pragma unroll
      for (int j = 0; j < 4; ++j) fbl[j] = *(const half8*)&sB[cur][1][boff + j * 512];
#pragma unroll
      for (int i = 0; i < 4; ++i)
#pragma unroll
        for (int j = 0; j < 4; ++j)
          acc[i][j] = __builtin_amdgcn_mfma_f32_16x16x32_f16(fa[i], fbl[j], acc[i][j], 0, 0, 0);
    }
    half8 fbh[4];
#pragma unroll
    for (int j = 0; j < 4; ++j) fbh[j] = *(const half8*)&sB[cur][0][boff + j * 512];
#pragma unroll
    for (int i = 0; i < 4; ++i)
#pragma unroll
      for (int j = 0; j < 4; ++j)
        acc[i][j] = __builtin_amdgcn_mfma_f32_16x16x32_f16(fa[i], fbh[j], acc[i][j], 0, 0, 0);
    if constexpr (SPLIT) {
      half8 fal[4];
#pragma unroll
      for (int i = 0; i < 4; ++i) fal[i] = *(const half8*)&sA[cur][1][aoff + i * 512];
#pragma unroll
      for (int i = 0; i < 4; ++i)
#pragma unroll
        for (int j = 0; j < 4; ++j)
          acc[i][j] = __builtin_amdgcn_mfma_f32_16x16x32_f16(fal[i], fbh[j], acc[i][j], 0, 0, 0);
    }
    // ONE sync per step: drains vmcnt(0)+lgkmcnt(0) then barrier.
    // - next buf's stage (issued ~1 compute-phase ago) has landed
    // - this wave's ds_reads of buf[cur] are complete, so stage(kt+2)
    //   (issued only after ALL waves pass this barrier) can't clobber them
    __syncthreads();
    cur ^= 1;
  }

  // epilogue: C/D layout col=lane&15, row=quad*4+r (m89/m91 verified)
  const int crow0 = m0 + wr * 64 + quad * 4;
  const int ccol0 = n0 + wc * 64 + l16;
#pragma unroll
  for (int j = 0; j < 4; ++j) {
    const int col = ccol0 + j * 16;
    float bj = 0.f;
    if constexpr (MODE == 0) bj = bias[col];
#pragma unroll
    for (int i = 0; i < 4; ++i) {
#pragma unroll
      for (int r = 0; r < 4; ++r) {
        const int row = crow0 + i * 16 + r;
        const size_t idx = zC + (size_t)row * N + col;
        float v = acc[i][j][r];
        if constexpr (MODE == 0) {
          v += bj;
          _Float16 h = (_Float16)v;
          Chi[idx] = f16bits(h);
          Clo[idx] = f16bits((_Float16)(v - (float)h));
        } else if constexpr (MODE == 1) {
          Cf[idx] = v + mask[idx];
        } else {
          Cf[idx] = v;
        }
      }
    }
  }
}

// ---------------- row softmax: fp32 scores -> f16 probs ----------------
__global__ __launch_bounds__(256) void softmax_kernel(
    const float* __restrict__ sc, uint16_t* __restrict__ p) {
  const int row = blockIdx.x;
  const float* x = sc + (size_t)row * 1024;
  const int t = threadIdx.x;
  float4 v = ((const float4*)x)[t];
  float m = fmaxf(fmaxf(v.x, v.y), fmaxf(v.z, v.w));
#pragma unroll
  for (int off = 32; off; off >>= 1) m = fmaxf(m, __shfl_xor(m, off));
  __shared__ float redm[4];
  __shared__ float reds[4];
  const int wv = t >> 6, ln = t & 63;
  if (ln == 0) redm[wv] = m;
  __syncthreads();
  m = fmaxf(fmaxf(redm[0], redm[1]), fmaxf(redm[2], redm[3]));
  float e0 = __expf(v.x - m), e1 = __expf(v.y - m);
  float e2 = __expf(v.z - m), e3 = __expf(v.w - m);
  float s = e0 + e1 + e2 + e3;
#pragma unroll
  for (int off = 32; off; off >>= 1) s += __shfl_xor(s, off);
  if (ln == 0) reds[wv] = s;
  __syncthreads();
  s = reds[0] + reds[1] + reds[2] + reds[3];
  float inv = 1.f / s;
  ushort4 o;
  o.x = f16bits((_Float16)(e0 * inv));
  o.y = f16bits((_Float16)(e1 * inv));
  o.z = f16bits((_Float16)(e2 * inv));
  o.w = f16bits((_Float16)(e3 * inv));
  ((ushort4*)(p + (size_t)row * 1024))[t] = o;
}

// ---------------- H (b,t,e) f32 -> H_T (b,e,t) f16 (fallback path) --------
__global__ __launch_bounds__(256) void transpose_f16_kernel(
    const float* __restrict__ src, uint16_t* __restrict__ dst) {
  __shared__ uint16_t tile[64][65];
  const int e0 = blockIdx.x * 64;
  const int t0 = blockIdx.y * 64;
  const size_t bb = (size_t)blockIdx.z << 20;
  const int r = threadIdx.x >> 4;
  const int c = (threadIdx.x & 15) * 4;
#pragma unroll
  for (int it = 0; it < 4; ++it) {
    const int tr = r + it * 16;
    float4 v = *(const float4*)(src + bb + (size_t)(t0 + tr) * 1024 + e0 + c);
    tile[c + 0][tr] = f16bits((_Float16)v.x);
    tile[c + 1][tr] = f16bits((_Float16)v.y);
    tile[c + 2][tr] = f16bits((_Float16)v.z);
    tile[c + 3][tr] = f16bits((_Float16)v.w);
  }
  __syncthreads();
#pragma unroll
  for (int it = 0; it < 4; ++it) {
    const int er = r + it * 16;
    ushort4 o;
    o.x = tile[er][c + 0];
    o.y = tile[er][c + 1];
    o.z = tile[er][c + 2];
    o.w = tile[er][c + 3];
    *(ushort4*)(dst + bb + (size_t)(e0 + er) * 1024 + t0 + c) = o;
  }
}

extern "C" void kernel_launch(void* const* d_in, const int* in_sizes, int n_in,
                              void* d_out, int out_size, void* d_ws, size_t ws_size,
                              hipStream_t stream) {
  (void)in_sizes; (void)n_in; (void)out_size;
  const float* S    = (const float*)d_in[0];  // (16,1024,1024)
  const float* H    = (const float*)d_in[1];  // (16,1024,1024)
  const float* mask = (const float*)d_in[2];  // (16,1024,1024)
  const float* Ww   = (const float*)d_in[3];  // (1024,1024)
  const float* Wb   = (const float*)d_in[4];  // (1024,)
  float* out = (float*)d_out;
  char* ws = (char*)d_ws;
  const size_t MB = 1024ull * 1024ull;

  // workspace layout:
  uint16_t* Whi  = (uint16_t*)(ws + 0 * MB);    // 2MB
  uint16_t* Wlo  = (uint16_t*)(ws + 2 * MB);    // 2MB
  uint16_t* Pjhi = (uint16_t*)(ws + 4 * MB);    // 32MB  projection hi
  uint16_t* Pjlo = (uint16_t*)(ws + 36 * MB);   // 32MB  projection lo
  uint16_t* Hhi  = (uint16_t*)(ws + 68 * MB);   // 32MB
  uint16_t* Hlo  = (uint16_t*)(ws + 100 * MB);  // 32MB
  uint16_t* Shi  = (uint16_t*)(ws + 132 * MB);  // 32MB (dead after gemm1)
  uint16_t* Slo  = (uint16_t*)(ws + 164 * MB);  // 32MB (dead after gemm1)
  float*    SC   = (float*)(ws + 132 * MB);     // 64MB scores, aliases Shi/Slo
  uint16_t* PR   = (uint16_t*)(ws + 68 * MB);   // 32MB probs, aliases Hhi

  const bool roomy = ws_size >= 229ull * MB;
  uint16_t* HT = roomy ? (uint16_t*)(ws + 196 * MB)   // 32MB dedicated
                       : (uint16_t*)(ws + 100 * MB);  // aliases Hlo (late write)

  // split inputs into f16 hi/lo
  split_f16_kernel<<<16384, 256, 0, stream>>>(S, Shi, Slo, 4 * 1024 * 1024);
  split_f16_kernel<<<1024, 256, 0, stream>>>(Ww, Whi, Wlo, 256 * 1024);
  if (roomy) {
    split_h_kernel<<<dim3(16, 16, 16), 256, 0, stream>>>(H, Hhi, Hlo, HT);
  } else {
    split_f16_kernel<<<16384, 256, 0, stream>>>(H, Hhi, Hlo, 4 * 1024 * 1024);
  }

  // S_ = S @ W^T + b   (GMAP 0: x = M-tile so lin%8 partitions A across XCDs)
  gemm_bt<true, 0, 0><<<dim3(128, 8, 1), 256, 0, stream>>>(
      Shi, Slo, Whi, Wlo, Pjhi, Pjlo, nullptr, nullptr, Wb,
      1024, 1024, 0, 0, 0);
  // scores = S_ @ H^T + mask  (GMAP 1: x = batch so lin%8 partitions batches)
  gemm_bt<true, 1, 1><<<dim3(16, 64, 1), 256, 0, stream>>>(
      Pjhi, Pjlo, Hhi, Hlo, nullptr, nullptr, SC, mask, nullptr,
      1024, 1024, 1048576, 1048576, 1048576);
  // P = softmax(scores) rowwise -> f16
  softmax_kernel<<<16384, 256, 0, stream>>>(SC, PR);
  if (!roomy) {
    transpose_f16_kernel<<<dim3(16, 16, 16), 256, 0, stream>>>(H, HT);
  }
  // out = P @ H  ==  P @ (H_T)^T
  gemm_bt<false, 2, 1><<<dim3(16, 64, 1), 256, 0, stream>>>(
      PR, nullptr, HT, nullptr, nullptr, nullptr, out, nullptr, nullptr,
      1024, 1024, 1048576, 1048576, 1048576);
}

// Round 5
// 499.600 us; speedup vs baseline: 1.1138x; 1.0134x over previous
//
#include <hip/hip_runtime.h>
#include <stdint.h>

typedef _Float16 half8 __attribute__((ext_vector_type(8)));
typedef float floatx4 __attribute__((ext_vector_type(4)));

__device__ __forceinline__ uint16_t f16bits(_Float16 h) {
  union { _Float16 f; uint16_t u; } x; x.f = h; return x.u;
}

// async global->LDS, 16B per lane; lds dst is wave-uniform base + lane*16
__device__ __forceinline__ void g2l16(const void* g, void* l) {
  __builtin_amdgcn_global_load_lds((const __attribute__((address_space(1))) void*)g,
                                   (__attribute__((address_space(3))) void*)l,
                                   16, 0, 0);
}

// ---------------- split fp32 -> f16 hi + f16 lo ----------------
__global__ __launch_bounds__(256) void split_f16_kernel(
    const float* __restrict__ x, uint16_t* __restrict__ hi,
    uint16_t* __restrict__ lo, int n4) {
  int i = blockIdx.x * 256 + threadIdx.x;
  if (i >= n4) return;
  float4 v = ((const float4*)x)[i];
  ushort4 h, l;
  _Float16 a;
  a = (_Float16)v.x; h.x = f16bits(a); l.x = f16bits((_Float16)(v.x - (float)a));
  a = (_Float16)v.y; h.y = f16bits(a); l.y = f16bits((_Float16)(v.y - (float)a));
  a = (_Float16)v.z; h.z = f16bits(a); l.z = f16bits((_Float16)(v.z - (float)a));
  a = (_Float16)v.w; h.w = f16bits(a); l.w = f16bits((_Float16)(v.w - (float)a));
  ((ushort4*)hi)[i] = h;
  ((ushort4*)lo)[i] = l;
}

// ---------------- fused H split + transpose ----------------
// H (b,t,e) f32 -> Hhi,Hlo (b,t,e) f16  AND  HT (b,e,t) f16(=hi)
__global__ __launch_bounds__(256) void split_h_kernel(
    const float* __restrict__ src, uint16_t* __restrict__ hi,
    uint16_t* __restrict__ lo, uint16_t* __restrict__ ht) {
  __shared__ uint16_t tile[64][65];
  const int e0 = blockIdx.x * 64;
  const int t0 = blockIdx.y * 64;
  const size_t bb = (size_t)blockIdx.z << 20;  // 1024*1024 per batch
  const int r = threadIdx.x >> 4;        // 0..15
  const int c = (threadIdx.x & 15) * 4;  // 0..60
#pragma unroll
  for (int it = 0; it < 4; ++it) {
    const int tr = r + it * 16;
    const size_t idx = bb + (size_t)(t0 + tr) * 1024 + e0 + c;
    float4 v = *(const float4*)(src + idx);
    ushort4 h, l;
    _Float16 a;
    a = (_Float16)v.x; h.x = f16bits(a); l.x = f16bits((_Float16)(v.x - (float)a));
    a = (_Float16)v.y; h.y = f16bits(a); l.y = f16bits((_Float16)(v.y - (float)a));
    a = (_Float16)v.z; h.z = f16bits(a); l.z = f16bits((_Float16)(v.z - (float)a));
    a = (_Float16)v.w; h.w = f16bits(a); l.w = f16bits((_Float16)(v.w - (float)a));
    *(ushort4*)(hi + idx) = h;
    *(ushort4*)(lo + idx) = l;
    tile[c + 0][tr] = h.x;
    tile[c + 1][tr] = h.y;
    tile[c + 2][tr] = h.z;
    tile[c + 3][tr] = h.w;
  }
  __syncthreads();
#pragma unroll
  for (int it = 0; it < 4; ++it) {
    const int er = r + it * 16;
    ushort4 o;
    o.x = tile[er][c + 0];
    o.y = tile[er][c + 1];
    o.z = tile[er][c + 2];
    o.w = tile[er][c + 3];
    *(ushort4*)(ht + bb + (size_t)(e0 + er) * 1024 + t0 + c) = o;
  }
}

// ------ C = A * B^T  (128x128 tile, BK=32, A-dbuf + B-single, 48KB) ------
// A:(M,K) row-major f16 (hi[,lo]), B:(N,K) row-major f16 (hi[,lo]).
// SPLIT: acc += Ahi*Blo + Ahi*Bhi + Alo*Bhi  (double-f16 ~ fp32 accuracy;
//        per-element order identical to baseline -> bit-identical output)
// Schedule per K-step (T3 dbuf for A + counted-vmcnt T4 for B):
//   stageB(kt) -> stageA(kt+1, other buf) -> ds_read fa (overlaps B flight)
//   -> s_waitcnt vmcnt(4) [B landed, A(kt+1) in flight] -> s_barrier
//   -> passes (fbl, fbh, fal) -> __syncthreads (drains A(kt+1), lgkm).
// LDS: SPLIT 48KB -> 3 blocks/CU; plain 24KB -> 4 blocks/CU (VGPR-limited).
// GMAP 0: x = M-tile (lin%8 partitions M across XCDs; W L2-resident)
// GMAP 1: x = batch (lin%8 partitions batches across XCDs), y = (m<<3)|n.
// MODE 0: write split f16 (Chi,Clo), add bias[col]
// MODE 1: write f32 Cf, add mask
// MODE 2: write f32 Cf
template <bool SPLIT, int MODE, int GMAP>
__global__ __launch_bounds__(256, 4) void gemm_bt(
    const uint16_t* __restrict__ Ahi, const uint16_t* __restrict__ Alo,
    const uint16_t* __restrict__ Bhi, const uint16_t* __restrict__ Blo,
    uint16_t* __restrict__ Chi, uint16_t* __restrict__ Clo,
    float* __restrict__ Cf, const float* __restrict__ mask,
    const float* __restrict__ bias, int N, int K,
    long batchA, long batchB, long batchC) {
  constexpr int NBUF = SPLIT ? 2 : 1;
  constexpr int LOI = SPLIT ? 1 : 0;
  // A: [dbuf][hi/lo][128 rows x 32 k]; B: single [hi/lo][128 x 32]
  __shared__ __align__(16) uint16_t sA[2][NBUF][128 * 32];
  __shared__ __align__(16) uint16_t sB[NBUF][128 * 32];

  const int tid = threadIdx.x;
  const int lane = tid & 63;
  const int w = tid >> 6;            // wave 0..3
  const int wr = w >> 1, wc = w & 1; // 2x2 wave grid, 64x64 per wave
  const int quad = lane >> 4, l16 = lane & 15;

  int m_t, n_t, z;
  if constexpr (GMAP == 0) {
    m_t = blockIdx.x; n_t = blockIdx.y; z = 0;
  } else {
    z = blockIdx.x; m_t = blockIdx.y >> 3; n_t = blockIdx.y & 7;
  }
  const int m0 = m_t * 128;
  const int n0 = n_t * 128;
  const size_t zA = (size_t)z * batchA;
  const size_t zB = (size_t)z * batchB;
  const size_t zC = (size_t)z * batchC;

  // staging: wave w loads rows [w*32, w*32+32) of each 128x32 tile, 2x 1KB
  const int r0 = w * 32 + (lane >> 2);                       // row for q=0 chunk
  const int ldc = (((lane & 3) ^ ((lane >> 2) & 3)) * 16);   // XOR-swizzled chunk

  const char* gAh0 = (const char*)(Ahi + zA + (size_t)(m0 + r0) * K) + ldc;
  const char* gAh1 = gAh0 + (size_t)16 * K * 2;
  const char* gBh0 = (const char*)(Bhi + zB + (size_t)(n0 + r0) * K) + ldc;
  const char* gBh1 = gBh0 + (size_t)16 * K * 2;
  const char* gAl0 = gAh0; const char* gAl1 = gAh1;
  const char* gBl0 = gBh0; const char* gBl1 = gBh1;
  if constexpr (SPLIT) {
    gAl0 = (const char*)(Alo + zA + (size_t)(m0 + r0) * K) + ldc;
    gAl1 = gAl0 + (size_t)16 * K * 2;
    gBl0 = (const char*)(Blo + zB + (size_t)(n0 + r0) * K) + ldc;
    gBl1 = gBl0 + (size_t)16 * K * 2;
  }

  auto stageA = [&](int buf, int kt) {
    const int kb = kt * 64;  // 32 f16 = 64B per row per K-tile
    g2l16(gAh0 + kb, &sA[buf][0][(w * 32) * 32]);
    g2l16(gAh1 + kb, &sA[buf][0][(w * 32 + 16) * 32]);
    if constexpr (SPLIT) {
      g2l16(gAl0 + kb, &sA[buf][LOI][(w * 32) * 32]);
      g2l16(gAl1 + kb, &sA[buf][LOI][(w * 32 + 16) * 32]);
    }
  };
  auto stageB = [&](int kt) {
    const int kb = kt * 64;
    g2l16(gBh0 + kb, &sB[0][(w * 32) * 32]);
    g2l16(gBh1 + kb, &sB[0][(w * 32 + 16) * 32]);
    if constexpr (SPLIT) {
      g2l16(gBl0 + kb, &sB[LOI][(w * 32) * 32]);
      g2l16(gBl1 + kb, &sB[LOI][(w * 32 + 16) * 32]);
    }
  };

  // compute-phase LDS offsets (elements); chunk swizzled by row&3 == l16&3
  const int aoff = (wr * 64 + l16) * 32 + ((quad ^ (l16 & 3)) * 8);
  const int boff = (wc * 64 + l16) * 32 + ((quad ^ (l16 & 3)) * 8);

  floatx4 acc[4][4];
  floatx4 zero = {0.f, 0.f, 0.f, 0.f};
#pragma unroll
  for (int i = 0; i < 4; ++i)
#pragma unroll
    for (int j = 0; j < 4; ++j) acc[i][j] = zero;

  const int nkt = K >> 5;
  // prologue: A(0) staged and drained (B(0) is staged inside the loop)
  stageA(0, 0);
  asm volatile("s_waitcnt vmcnt(0)" ::: "memory");
  __builtin_amdgcn_s_barrier();
  asm volatile("" ::: "memory");

  int cur = 0;
  for (int kt = 0; kt < nkt; ++kt) {
    stageB(kt);                                   // into single B buffer
    const bool pre = (kt + 1 < nkt);
    if (pre) stageA(cur ^ 1, kt + 1);             // prefetch next A (dbuf)

    // A-hi fragments: reads overlap B's in-flight window (A[cur] is stable)
    half8 fa[4];
#pragma unroll
    for (int i = 0; i < 4; ++i) fa[i] = *(const half8*)&sA[cur][0][aoff + i * 512];

    // wait B landed (counted: A(kt+1) stays in flight), then barrier so ALL
    // waves' B writes are visible
    if (pre) {
      if constexpr (SPLIT)
        asm volatile("s_waitcnt vmcnt(4)" ::: "memory");
      else
        asm volatile("s_waitcnt vmcnt(2)" ::: "memory");
    } else {
      asm volatile("s_waitcnt vmcnt(0)" ::: "memory");
    }
    __builtin_amdgcn_s_barrier();
    asm volatile("" ::: "memory");  // B reads must not hoist above barrier

    // 3 sequential product passes -> max ~2x4 half8 frags live
    if constexpr (SPLIT) {
      half8 fbl[4];
#pragma unroll
      for (int j = 0; j < 4; ++j) fbl[j] = *(const half8*)&sB[1][boff + j * 512];
#pragma unroll
      for (int i = 0; i < 4; ++i)
#pragma unroll
        for (int j = 0; j < 4; ++j)
          acc[i][j] = __builtin_amdgcn_mfma_f32_16x16x32_f16(fa[i], fbl[j], acc[i][j], 0, 0, 0);
    }
    half8 fbh[4];
#pragma unroll
    for (int j = 0; j < 4; ++j) fbh[j] = *(const half8*)&sB[0][boff + j * 512];
#pragma unroll
    for (int i = 0; i < 4; ++i)
#pragma unroll
      for (int j = 0; j < 4; ++j)
        acc[i][j] = __builtin_amdgcn_mfma_f32_16x16x32_f16(fa[i], fbh[j], acc[i][j], 0, 0, 0);
    if constexpr (SPLIT) {
      half8 fal[4];
#pragma unroll
      for (int i = 0; i < 4; ++i) fal[i] = *(const half8*)&sA[cur][1][aoff + i * 512];
#pragma unroll
      for (int i = 0; i < 4; ++i)
#pragma unroll
        for (int j = 0; j < 4; ++j)
          acc[i][j] = __builtin_amdgcn_mfma_f32_16x16x32_f16(fal[i], fbh[j], acc[i][j], 0, 0, 0);
    }
    // end-of-step: drains vmcnt(0)+lgkmcnt(0) then barrier =>
    //  - A(kt+1) landed; all waves' reads of sB/sA[cur] complete, so next
    //    step's stageB / stageA(kt+2) can't clobber live data
    __syncthreads();
    cur ^= 1;
  }

  // epilogue: C/D layout col=lane&15, row=quad*4+r (m89/m91 verified)
  const int crow0 = m0 + wr * 64 + quad * 4;
  const int ccol0 = n0 + wc * 64 + l16;
#pragma unroll
  for (int j = 0; j < 4; ++j) {
    const int col = ccol0 + j * 16;
    float bj = 0.f;
    if constexpr (MODE == 0) bj = bias[col];
#pragma unroll
    for (int i = 0; i < 4; ++i) {
#pragma unroll
      for (int r = 0; r < 4; ++r) {
        const int row = crow0 + i * 16 + r;
        const size_t idx = zC + (size_t)row * N + col;
        float v = acc[i][j][r];
        if constexpr (MODE == 0) {
          v += bj;
          _Float16 h = (_Float16)v;
          Chi[idx] = f16bits(h);
          Clo[idx] = f16bits((_Float16)(v - (float)h));
        } else if constexpr (MODE == 1) {
          Cf[idx] = v + mask[idx];
        } else {
          Cf[idx] = v;
        }
      }
    }
  }
}

// ---------------- row softmax: fp32 scores -> f16 probs ----------------
__global__ __launch_bounds__(256) void softmax_kernel(
    const float* __restrict__ sc, uint16_t* __restrict__ p) {
  const int row = blockIdx.x;
  const float* x = sc + (size_t)row * 1024;
  const int t = threadIdx.x;
  float4 v = ((const float4*)x)[t];
  float m = fmaxf(fmaxf(v.x, v.y), fmaxf(v.z, v.w));
#pragma unroll
  for (int off = 32; off; off >>= 1) m = fmaxf(m, __shfl_xor(m, off));
  __shared__ float redm[4];
  __shared__ float reds[4];
  const int wv = t >> 6, ln = t & 63;
  if (ln == 0) redm[wv] = m;
  __syncthreads();
  m = fmaxf(fmaxf(redm[0], redm[1]), fmaxf(redm[2], redm[3]));
  float e0 = __expf(v.x - m), e1 = __expf(v.y - m);
  float e2 = __expf(v.z - m), e3 = __expf(v.w - m);
  float s = e0 + e1 + e2 + e3;
#pragma unroll
  for (int off = 32; off; off >>= 1) s += __shfl_xor(s, off);
  if (ln == 0) reds[wv] = s;
  __syncthreads();
  s = reds[0] + reds[1] + reds[2] + reds[3];
  float inv = 1.f / s;
  ushort4 o;
  o.x = f16bits((_Float16)(e0 * inv));
  o.y = f16bits((_Float16)(e1 * inv));
  o.z = f16bits((_Float16)(e2 * inv));
  o.w = f16bits((_Float16)(e3 * inv));
  ((ushort4*)(p + (size_t)row * 1024))[t] = o;
}

// ---------------- H (b,t,e) f32 -> H_T (b,e,t) f16 (fallback path) --------
__global__ __launch_bounds__(256) void transpose_f16_kernel(
    const float* __restrict__ src, uint16_t* __restrict__ dst) {
  __shared__ uint16_t tile[64][65];
  const int e0 = blockIdx.x * 64;
  const int t0 = blockIdx.y * 64;
  const size_t bb = (size_t)blockIdx.z << 20;
  const int r = threadIdx.x >> 4;
  const int c = (threadIdx.x & 15) * 4;
#pragma unroll
  for (int it = 0; it < 4; ++it) {
    const int tr = r + it * 16;
    float4 v = *(const float4*)(src + bb + (size_t)(t0 + tr) * 1024 + e0 + c);
    tile[c + 0][tr] = f16bits((_Float16)v.x);
    tile[c + 1][tr] = f16bits((_Float16)v.y);
    tile[c + 2][tr] = f16bits((_Float16)v.z);
    tile[c + 3][tr] = f16bits((_Float16)v.w);
  }
  __syncthreads();
#pragma unroll
  for (int it = 0; it < 4; ++it) {
    const int er = r + it * 16;
    ushort4 o;
    o.x = tile[er][c + 0];
    o.y = tile[er][c + 1];
    o.z = tile[er][c + 2];
    o.w = tile[er][c + 3];
    *(ushort4*)(dst + bb + (size_t)(e0 + er) * 1024 + t0 + c) = o;
  }
}

extern "C" void kernel_launch(void* const* d_in, const int* in_sizes, int n_in,
                              void* d_out, int out_size, void* d_ws, size_t ws_size,
                              hipStream_t stream) {
  (void)in_sizes; (void)n_in; (void)out_size;
  const float* S    = (const float*)d_in[0];  // (16,1024,1024)
  const float* H    = (const float*)d_in[1];  // (16,1024,1024)
  const float* mask = (const float*)d_in[2];  // (16,1024,1024)
  const float* Ww   = (const float*)d_in[3];  // (1024,1024)
  const float* Wb   = (const float*)d_in[4];  // (1024,)
  float* out = (float*)d_out;
  char* ws = (char*)d_ws;
  const size_t MB = 1024ull * 1024ull;

  // workspace layout:
  uint16_t* Whi  = (uint16_t*)(ws + 0 * MB);    // 2MB
  uint16_t* Wlo  = (uint16_t*)(ws + 2 * MB);    // 2MB
  uint16_t* Pjhi = (uint16_t*)(ws + 4 * MB);    // 32MB  projection hi
  uint16_t* Pjlo = (uint16_t*)(ws + 36 * MB);   // 32MB  projection lo
  uint16_t* Hhi  = (uint16_t*)(ws + 68 * MB);   // 32MB
  uint16_t* Hlo  = (uint16_t*)(ws + 100 * MB);  // 32MB
  uint16_t* Shi  = (uint16_t*)(ws + 132 * MB);  // 32MB (dead after gemm1)
  uint16_t* Slo  = (uint16_t*)(ws + 164 * MB);  // 32MB (dead after gemm1)
  float*    SC   = (float*)(ws + 132 * MB);     // 64MB scores, aliases Shi/Slo
  uint16_t* PR   = (uint16_t*)(ws + 68 * MB);   // 32MB probs, aliases Hhi

  const bool roomy = ws_size >= 229ull * MB;
  uint16_t* HT = roomy ? (uint16_t*)(ws + 196 * MB)   // 32MB dedicated
                       : (uint16_t*)(ws + 100 * MB);  // aliases Hlo (late write)

  // split inputs into f16 hi/lo
  split_f16_kernel<<<16384, 256, 0, stream>>>(S, Shi, Slo, 4 * 1024 * 1024);
  split_f16_kernel<<<1024, 256, 0, stream>>>(Ww, Whi, Wlo, 256 * 1024);
  if (roomy) {
    split_h_kernel<<<dim3(16, 16, 16), 256, 0, stream>>>(H, Hhi, Hlo, HT);
  } else {
    split_f16_kernel<<<16384, 256, 0, stream>>>(H, Hhi, Hlo, 4 * 1024 * 1024);
  }

  // S_ = S @ W^T + b   (GMAP 0: x = M-tile so lin%8 partitions A across XCDs)
  gemm_bt<true, 0, 0><<<dim3(128, 8, 1), 256, 0, stream>>>(
      Shi, Slo, Whi, Wlo, Pjhi, Pjlo, nullptr, nullptr, Wb,
      1024, 1024, 0, 0, 0);
  // scores = S_ @ H^T + mask  (GMAP 1: x = batch so lin%8 partitions batches)
  gemm_bt<true, 1, 1><<<dim3(16, 64, 1), 256, 0, stream>>>(
      Pjhi, Pjlo, Hhi, Hlo, nullptr, nullptr, SC, mask, nullptr,
      1024, 1024, 1048576, 1048576, 1048576);
  // P = softmax(scores) rowwise -> f16
  softmax_kernel<<<16384, 256, 0, stream>>>(SC, PR);
  if (!roomy) {
    transpose_f16_kernel<<<dim3(16, 16, 16), 256, 0, stream>>>(H, HT);
  }
  // out = P @ H  ==  P @ (H_T)^T
  gemm_bt<false, 2, 1><<<dim3(16, 64, 1), 256, 0, stream>>>(
      PR, nullptr, HT, nullptr, nullptr, nullptr, out, nullptr, nullptr,
      1024, 1024, 1048576, 1048576, 1048576);
}